// Round 1
// baseline (637.695 us; speedup 1.0000x reference)
//
#include <hip/hip_runtime.h>
#include <hip/hip_bf16.h>
#include <cstdint>
#include <cstddef>

// Problem constants (from reference setup_inputs)
constexpr int BROWS = 4096;    // batch rows
constexpr int MREAL = 12893;   // prototypes
constexpr int MPAD  = 12928;   // 101 * 128, zero-padded
constexpr int KDIM  = 2048;

typedef __attribute__((ext_vector_type(8))) short short8;   // 8 x bf16 (4 VGPRs)
typedef __attribute__((ext_vector_type(4))) float f32x4;    // MFMA accumulator

// Async global->LDS, 16B per lane. LDS dest = wave-uniform base + lane*16,
// so LDS offsets MUST be tid*16-contiguous per wave (they are below).
__device__ __forceinline__ void gld_lds16(const void* g, void* l) {
  __builtin_amdgcn_global_load_lds((__attribute__((address_space(1))) const void*)g,
                                   (__attribute__((address_space(3))) void*)l,
                                   16, 0, 0);
}

// ---------------------------------------------------------------------------
// Row-wise L2 normalize fp32 -> bf16. One block (256 thr) per row, D=2048.
// Rows >= nvalid are zero-filled (padding rows for the GEMM N dimension).
// ---------------------------------------------------------------------------
__global__ void l2norm_bf16(const float* __restrict__ in,
                            __hip_bfloat16* __restrict__ out,
                            int nvalid) {
  const int row = blockIdx.x;
  const int t   = threadIdx.x;
  __hip_bfloat16* orow = out + (size_t)row * KDIM;

  if (row >= nvalid) {
    // 2048 bf16 = 4096 B = 256 threads * 16 B
    reinterpret_cast<float4*>(orow)[t] = make_float4(0.f, 0.f, 0.f, 0.f);
    return;
  }

  const float4* irow = reinterpret_cast<const float4*>(in + (size_t)row * KDIM);
  float4 a = irow[t];        // elements 4t .. 4t+3
  float4 b = irow[t + 256];  // elements 1024+4t ..
  float ss = a.x*a.x + a.y*a.y + a.z*a.z + a.w*a.w
           + b.x*b.x + b.y*b.y + b.z*b.z + b.w*b.w;

  #pragma unroll
  for (int off = 32; off > 0; off >>= 1) ss += __shfl_down(ss, off);

  __shared__ float red[4];
  if ((t & 63) == 0) red[t >> 6] = ss;
  __syncthreads();
  float tot = red[0] + red[1] + red[2] + red[3];
  // F.normalize: v / max(||v||, eps)
  float inv = 1.0f / fmaxf(sqrtf(tot), 1e-12f);

  union { ushort4 u; __hip_bfloat16 h[4]; } o1, o2;
  o1.h[0] = __float2bfloat16(a.x * inv);
  o1.h[1] = __float2bfloat16(a.y * inv);
  o1.h[2] = __float2bfloat16(a.z * inv);
  o1.h[3] = __float2bfloat16(a.w * inv);
  o2.h[0] = __float2bfloat16(b.x * inv);
  o2.h[1] = __float2bfloat16(b.y * inv);
  o2.h[2] = __float2bfloat16(b.z * inv);
  o2.h[3] = __float2bfloat16(b.w * inv);
  reinterpret_cast<ushort4*>(orow)[t]       = o1.u;
  reinterpret_cast<ushort4*>(orow)[t + 256] = o2.u;
}

// ---------------------------------------------------------------------------
// C[b,m] = -|s| * sqrt(max(2 - 2 * dot(xn[b], pn[m]), 0))
// m97 structure: 128x128 tile, BK=32, 4 waves in 2x2, each wave 4x4 tiles of
// mfma_f32_16x16x32_bf16; global_load_lds width=16 staging; fused epilogue.
// A: [BROWS][KDIM] bf16 row-major. P: [MPAD][KDIM] bf16 row-major (B^T form).
// ---------------------------------------------------------------------------
__global__ void gemm_dist(const __hip_bfloat16* __restrict__ A,
                          const __hip_bfloat16* __restrict__ P,
                          const float* __restrict__ scale,
                          float* __restrict__ out) {
  __shared__ __hip_bfloat16 sA[128][32];  // 8 KB
  __shared__ __hip_bfloat16 sB[128][32];  // 8 KB

  const int tid  = threadIdx.x;       // 256 threads = 4 waves
  const int lane = tid & 63;
  const int wave = tid >> 6;
  const int wm   = wave >> 1;         // 0..1 : wave row in 2x2
  const int wn   = wave & 1;          // 0..1 : wave col
  const int bm0  = blockIdx.y * 128;
  const int bn0  = blockIdx.x * 128;

  f32x4 acc[4][4];
  #pragma unroll
  for (int i = 0; i < 4; i++)
    #pragma unroll
    for (int j = 0; j < 4; j++)
      acc[i][j] = f32x4{0.f, 0.f, 0.f, 0.f};

  // Staging map: thread t covers tile row t/4, cols (t%4)*8 .. +8 (16 B).
  // LDS byte offset = tid*16 -> wave-contiguous as global_load_lds requires.
  const int sr = tid >> 2;            // 0..63
  const int sc = (tid & 3) << 3;      // 0,8,16,24

  // Fragment map (A-operand layout: row = lane&15, k = (lane>>4)*8 .. +8)
  const int frow = lane & 15;
  const int koff = (lane >> 4) << 3;

  for (int kt = 0; kt < KDIM; kt += 32) {
    __syncthreads();  // previous iteration's LDS reads complete
    gld_lds16(A + (size_t)(bm0 + sr)      * KDIM + kt + sc, &sA[sr][sc]);
    gld_lds16(A + (size_t)(bm0 + sr + 64) * KDIM + kt + sc, &sA[sr + 64][sc]);
    gld_lds16(P + (size_t)(bn0 + sr)      * KDIM + kt + sc, &sB[sr][sc]);
    gld_lds16(P + (size_t)(bn0 + sr + 64) * KDIM + kt + sc, &sB[sr + 64][sc]);
    __syncthreads();  // compiler emits s_waitcnt vmcnt(0) before s_barrier

    short8 af[4], bf[4];
    #pragma unroll
    for (int i = 0; i < 4; i++)
      af[i] = *reinterpret_cast<const short8*>(&sA[wm * 64 + i * 16 + frow][koff]);
    #pragma unroll
    for (int j = 0; j < 4; j++)
      bf[j] = *reinterpret_cast<const short8*>(&sB[wn * 64 + j * 16 + frow][koff]);

    #pragma unroll
    for (int i = 0; i < 4; i++)
      #pragma unroll
      for (int j = 0; j < 4; j++)
        acc[i][j] = __builtin_amdgcn_mfma_f32_16x16x32_bf16(af[i], bf[j],
                                                            acc[i][j], 0, 0, 0);
  }

  // Epilogue: C/D layout col = lane&15, row = (lane>>4)*4 + reg  [m89/m91]
  const float s = fabsf(scale[0]);
  const int colb = bn0 + wn * 64 + (lane & 15);
  #pragma unroll
  for (int i = 0; i < 4; i++) {
    const int rowb = bm0 + wm * 64 + i * 16 + ((lane >> 4) << 2);
    #pragma unroll
    for (int j = 0; j < 4; j++) {
      const int col = colb + j * 16;
      if (col < MREAL) {
        #pragma unroll
        for (int r = 0; r < 4; r++) {
          float d2 = fmaxf(2.0f - 2.0f * acc[i][j][r], 0.0f);
          out[(size_t)(rowb + r) * MREAL + col] = -s * __builtin_sqrtf(d2);
        }
      }
    }
  }
}

// ---------------------------------------------------------------------------
extern "C" void kernel_launch(void* const* d_in, const int* in_sizes, int n_in,
                              void* d_out, int out_size, void* d_ws, size_t ws_size,
                              hipStream_t stream) {
  const float* x = (const float*)d_in[0];          // [4096, 2048] fp32
  const float* p = (const float*)d_in[1];          // [12893, 2048] fp32
  const float* s = (const float*)d_in[2];          // [1] fp32
  float* out = (float*)d_out;                      // [4096, 12893] fp32

  // Workspace: xn bf16 [4096][2048] then pn bf16 [12928][2048]  (~66.5 MB)
  __hip_bfloat16* xn = (__hip_bfloat16*)d_ws;
  __hip_bfloat16* pn = xn + (size_t)BROWS * KDIM;

  l2norm_bf16<<<BROWS, 256, 0, stream>>>(x, xn, BROWS);
  l2norm_bf16<<<MPAD,  256, 0, stream>>>(p, pn, MREAL);

  dim3 grid(MPAD / 128, BROWS / 128);  // (101, 32) = 3232 blocks
  gemm_dist<<<grid, 256, 0, stream>>>(xn, pn, s, out);
}